// Round 7
// baseline (41.449 us; speedup 1.0000x reference)
//
#include <hip/hip_runtime.h>
#include <math.h>

struct V2 { float x, y; };

#define NT 256

// angle class matching atan2 range ordering: 0: y<0 (-pi,0); 1: y==0,x>=0 {0};
// 2: y>0 (0,pi); 3: y==0,x<0 {pi}
__device__ __forceinline__ int ang_class(float x, float y) {
    return (y < 0.f) ? 0 : ((y > 0.f) ? 2 : ((x >= 0.f) ? 1 : 3));
}

// Ascending sort of 4 points by exact atan2 ordering around the centroid,
// as a 5-comparator network. Comparator is exact (f64 cross), so it deviates
// from jnp.argsort only on exact angle ties (measure zero).
__device__ __forceinline__ void angle_sort4(float4 lo, float4 hi, V2 out[4]) {
    float x[4] = {lo.x, lo.z, hi.x, hi.z};
    float y[4] = {lo.y, lo.w, hi.y, hi.w};
    float cx = (((x[0] + x[1]) + x[2]) + x[3]) * 0.25f;
    float cy = (((y[0] + y[1]) + y[2]) + y[3]) * 0.25f;
    float rx[4], ry[4]; int cl[4];
#pragma unroll
    for (int i = 0; i < 4; i++) {
        rx[i] = x[i] - cx; ry[i] = y[i] - cy;
        cl[i] = ang_class(rx[i], ry[i]);
    }
#define CE(i, j) { \
    int cd = cl[i] - cl[j]; \
    double cr = (double)rx[i] * (double)ry[j] - (double)ry[i] * (double)rx[j]; \
    bool gt = (cd > 0) || (cd == 0 && cr < 0.0);  /* ang_i > ang_j -> swap */ \
    float t; int ti; \
    t = x[i];  x[i]  = gt ? x[j]  : x[i];  x[j]  = gt ? t  : x[j]; \
    t = y[i];  y[i]  = gt ? y[j]  : y[i];  y[j]  = gt ? t  : y[j]; \
    t = rx[i]; rx[i] = gt ? rx[j] : rx[i]; rx[j] = gt ? t  : rx[j]; \
    t = ry[i]; ry[i] = gt ? ry[j] : ry[i]; ry[j] = gt ? t  : ry[j]; \
    ti = cl[i]; cl[i] = gt ? cl[j] : cl[i]; cl[j] = gt ? ti : cl[j]; \
}
    CE(0, 1) CE(2, 3) CE(0, 2) CE(1, 3) CE(1, 2)
#undef CE
#pragma unroll
    for (int k = 0; k < 4; k++) { out[k].x = x[k]; out[k].y = y[k]; }
}

// One Sutherland-Hodgman round, IN-PLACE in LDS. All emissions are
// unconditional ds_writes; invalid ones land in trash row 8 (branch-free).
__device__ __forceinline__ int clip_mid(float2 (*buf)[NT], V2 A, V2 B,
                                        int nv, int tid)
{
    float ex = B.x - A.x, ey = B.y - A.y;
    float qx[8], qy[8], d[8];
#pragma unroll
    for (int s = 0; s < 8; s++) {
        float2 v = buf[s][tid];
        qx[s] = v.x; qy[s] = v.y;
        d[s] = ex * (v.y - A.y) - ey * (v.x - A.x);
    }
    int cnt = 0;
#pragma unroll
    for (int idx = 0; idx < 8; idx++) {
        // next vertex: replicates poly[(idx+1) % max(nv,1)] with JAX index-clamp
        float nxx, nxy, dn;
        if (idx == 7) {
            bool w = (nv == 8);          // nv>8 -> index 8 clamps to slot 7 (self)
            nxx = w ? qx[0] : qx[7];
            nxy = w ? qy[0] : qy[7];
            dn  = w ? d[0]  : d[7];
        } else {
            bool w = ((idx + 1) == nv);
            nxx = w ? qx[0] : qx[idx + 1];
            nxy = w ? qy[0] : qy[idx + 1];
            dn  = w ? d[0]  : d[idx + 1];
        }
        bool active = idx < nv;
        bool in_cur = d[idx] >= 0.f;
        bool in_nxt = dn >= 0.f;
        float den = d[idx] - dn;
        den = (fabsf(den) < 1e-12f) ? 1e-12f : den;
        float t = __fdividef(d[idx], den);
        float ix = qx[idx] + t * (nxx - qx[idx]);
        float iy = qy[idx] + t * (nxy - qy[idx]);
        bool v0 = active && in_cur;
        bool v1 = active && (in_cur != in_nxt);
        int s0 = (v0 && cnt < 8) ? cnt : 8;
        buf[s0][tid] = make_float2(qx[idx], qy[idx]);
        cnt += v0 ? 1 : 0;
        int s1 = (v1 && cnt < 8) ? cnt : 8;
        buf[s1][tid] = make_float2(ix, iy);
        cnt += v1 ? 1 : 0;
    }
    return cnt;   // unclamped count, like the reference
}

// Final round: clip fused with shoelace over emitted points (no LDS writes).
// Emission order == slot order; wrap term added last == reference FP sum order.
__device__ __forceinline__ float clip_final(const float2 (*buf)[NT], V2 A, V2 B,
                                            int nv, int tid)
{
    float ex = B.x - A.x, ey = B.y - A.y;
    float qx[8], qy[8], d[8];
#pragma unroll
    for (int s = 0; s < 8; s++) {
        float2 v = buf[s][tid];
        qx[s] = v.x; qy[s] = v.y;
        d[s] = ex * (v.y - A.y) - ey * (v.x - A.x);
    }
    int cnt = 0;
    float sx = 0.f;
    float fx = 0.f, fy = 0.f;   // first kept point
    float px = 0.f, py = 0.f;   // prev kept point (slot <= 7)
#pragma unroll
    for (int idx = 0; idx < 8; idx++) {
        float nxx, nxy, dn;
        if (idx == 7) {
            bool w = (nv == 8);
            nxx = w ? qx[0] : qx[7];
            nxy = w ? qy[0] : qy[7];
            dn  = w ? d[0]  : d[7];
        } else {
            bool w = ((idx + 1) == nv);
            nxx = w ? qx[0] : qx[idx + 1];
            nxy = w ? qy[0] : qy[idx + 1];
            dn  = w ? d[0]  : d[idx + 1];
        }
        bool active = idx < nv;
        bool in_cur = d[idx] >= 0.f;
        bool in_nxt = dn >= 0.f;
        float den = d[idx] - dn;
        den = (fabsf(den) < 1e-12f) ? 1e-12f : den;
        float t = __fdividef(d[idx], den);
        float ix = qx[idx] + t * (nxx - qx[idx]);
        float iy = qy[idx] + t * (nxy - qy[idx]);
        bool v0 = active && in_cur;
        bool v1 = active && (in_cur != in_nxt);
        {
            bool w0 = (cnt == 0), wl = (cnt <= 7);
            if (v0) {
                fx = w0 ? qx[idx] : fx; fy = w0 ? qy[idx] : fy;
                sx += (!w0 && wl) ? (px * qy[idx] - qx[idx] * py) : 0.f;
                px = wl ? qx[idx] : px; py = wl ? qy[idx] : py;
            }
            cnt += v0 ? 1 : 0;
        }
        {
            bool w0 = (cnt == 0), wl = (cnt <= 7);
            if (v1) {
                fx = w0 ? ix : fx; fy = w0 ? iy : fy;
                sx += (!w0 && wl) ? (px * iy - ix * py) : 0.f;
                px = wl ? ix : px; py = wl ? iy : py;
            }
            cnt += v1 ? 1 : 0;
        }
    }
    // wrap term (ref: idx nv-1 pairs poly[0]); nv>8 -> slot7 pairs itself (0)
    if (cnt > 0 && cnt <= 8) sx += px * fy - fx * py;
    return 0.5f * fabsf(sx);
}

// tournament candidate: rel vector (for cross), d2 (validity/tie), abs coords
struct Cand { float rx, ry, d2, px, py; };

// most-clockwise comparator; null candidates carry d2 = -1 (rel = 0,0)
__device__ __forceinline__ Cand mcw(Cand a, Cand b) {
    float c = a.rx * b.ry - a.ry * b.rx;
    // null a: rel=(0,0) -> c==0, b.d2 > a.d2 -> take b. null b: d2<0 -> keep a.
    bool tb = (b.d2 > 0.f) && ((c < 0.f) || ((c == 0.f) && (b.d2 > a.d2)));
    Cand o;
    o.rx = tb ? b.rx : a.rx; o.ry = tb ? b.ry : a.ry; o.d2 = tb ? b.d2 : a.d2;
    o.px = tb ? b.px : a.px; o.py = tb ? b.py : a.py;
    return o;
}

__global__ __launch_bounds__(256, 8) void poly_iou_kernel(
    const float* __restrict__ preds, const float* __restrict__ targets,
    float* __restrict__ out, int n)
{
    __shared__ float2 buf[9][NT];   // 18 KB: 8 slots + 1 trash row per thread
    int tid = threadIdx.x;
    int gid = blockIdx.x * NT + tid;
    if (gid >= n) return;

    const float4* p4 = reinterpret_cast<const float4*>(preds);
    const float4* t4 = reinterpret_cast<const float4*>(targets);
    float4 a0 = p4[2 * gid], a1 = p4[2 * gid + 1];
    float4 b0 = t4[2 * gid], b1 = t4[2 * gid + 1];

    V2 P[4], T[4];
    angle_sort4(a0, a1, P);
    angle_sort4(b0, b1, T);

    // ---- edge 0 (nv=4 compile-time): registers -> buf, branch-free emits ----
    int nv;
    {
        float ex = T[1].x - T[0].x, ey = T[1].y - T[0].y;
        float dd[4];
#pragma unroll
        for (int k = 0; k < 4; k++)
            dd[k] = ex * (P[k].y - T[0].y) - ey * (P[k].x - T[0].x);
        int cnt = 0;
#pragma unroll
        for (int idx = 0; idx < 4; idx++) {
            int j = (idx + 1) & 3;
            bool in_cur = dd[idx] >= 0.f;
            bool in_nxt = dd[j] >= 0.f;
            float den = dd[idx] - dd[j];
            den = (fabsf(den) < 1e-12f) ? 1e-12f : den;
            float t = __fdividef(dd[idx], den);
            float ix = P[idx].x + t * (P[j].x - P[idx].x);
            float iy = P[idx].y + t * (P[j].y - P[idx].y);
            bool v1 = (in_cur != in_nxt);
            int s0 = in_cur ? cnt : 8;              // cnt <= 7 here always
            buf[s0][tid] = make_float2(P[idx].x, P[idx].y);
            cnt += in_cur ? 1 : 0;
            int s1 = v1 ? cnt : 8;
            buf[s1][tid] = make_float2(ix, iy);
            cnt += v1 ? 1 : 0;
        }
        nv = cnt;
    }

    // ---- edges 1..2 in place; edge 3 fused with shoelace ----
    nv = clip_mid(buf, T[1], T[2], nv, tid);
    nv = clip_mid(buf, T[2], T[3], nv, tid);
    float inter = clip_final(buf, T[3], T[0], nv, tid);

    // ---- convex hull area (gift wrap, tree-reduced scan, exact coords) ----
    float hx[8], hy[8];
#pragma unroll
    for (int k = 0; k < 4; k++) {
        hx[k] = P[k].x; hy[k] = P[k].y;
        hx[4 + k] = T[k].x; hy[4 + k] = T[k].y;
    }

    float vsx = hx[0], vsy = hy[0];
#pragma unroll
    for (int k = 1; k < 8; k++) {           // first-index argmin of y
        bool b = hy[k] < vsy;
        vsx = b ? hx[k] : vsx;
        vsy = b ? hy[k] : vsy;
    }

    float pcx = vsx, pcy = vsy;
    bool done = false;
    float harea = 0.f;
#pragma unroll
    for (int s = 0; s < 8; s++) {
        Cand c[8];
#pragma unroll
        for (int k = 0; k < 8; k++) {
            float ux = hx[k] - pcx, uy = hy[k] - pcy;
            float dd = ux * ux + uy * uy;
            bool ok = dd > 1e-12f;
            c[k].rx = ok ? ux : 0.f;
            c[k].ry = ok ? uy : 0.f;
            c[k].d2 = ok ? dd : -1.f;
            c[k].px = hx[k]; c[k].py = hy[k];
        }
        Cand w01 = mcw(c[0], c[1]), w23 = mcw(c[2], c[3]);
        Cand w45 = mcw(c[4], c[5]), w67 = mcw(c[6], c[7]);
        Cand wA = mcw(w01, w23), wB = mcw(w45, w67);
        Cand w = mcw(wA, wB);

        bool stay = done || (w.d2 < 0.f);
        float pvx = stay ? pcx : w.px;      // EXACT h[k] coords (bug fix)
        float pvy = stay ? pcy : w.py;
        harea += pcx * pvy - pvx * pcy;     // stay-steps add exact 0
        done = done || ((pvx == vsx) && (pvy == vsy));
        pcx = pvx; pcy = pvy;
    }
    harea += pcx * vsy - vsx * pcy;         // closure
    harea = 0.5f * fabsf(harea);

    float iou = (harea > 1e-12f) ? (inter / fmaxf(harea, 1e-12f)) : 0.f;
    out[gid] = 1.f - iou;
}

extern "C" void kernel_launch(void* const* d_in, const int* in_sizes, int n_in,
                              void* d_out, int out_size, void* d_ws, size_t ws_size,
                              hipStream_t stream) {
    const float* preds = (const float*)d_in[0];
    const float* targets = (const float*)d_in[1];
    float* out = (float*)d_out;
    int n = in_sizes[0] / 8;
    int block = NT;
    int grid = (n + block - 1) / block;
    hipLaunchKernelGGL(poly_iou_kernel, dim3(grid), dim3(block), 0, stream,
                       preds, targets, out, n);
}

// Round 8
// 33.741 us; speedup vs baseline: 1.2285x; 1.2285x over previous
//
#include <hip/hip_runtime.h>
#include <math.h>

struct V2 { float x, y; };

#define NT 256

// angle class matching atan2 range ordering: 0: y<0 (-pi,0); 1: y==0,x>=0 {0};
// 2: y>0 (0,pi); 3: y==0,x<0 {pi}
__device__ __forceinline__ int ang_class(float x, float y) {
    return (y < 0.f) ? 0 : ((y > 0.f) ? 2 : ((x >= 0.f) ? 1 : 3));
}

// Ascending sort of 4 points by exact atan2 ordering around the centroid,
// as a 5-comparator network. Comparator is exact (f64 cross), deviating from
// jnp.argsort only on exact angle ties (measure zero).
__device__ __forceinline__ void angle_sort4(float4 lo, float4 hi, V2 out[4]) {
    float x[4] = {lo.x, lo.z, hi.x, hi.z};
    float y[4] = {lo.y, lo.w, hi.y, hi.w};
    float cx = (((x[0] + x[1]) + x[2]) + x[3]) * 0.25f;
    float cy = (((y[0] + y[1]) + y[2]) + y[3]) * 0.25f;
    float rx[4], ry[4]; int cl[4];
#pragma unroll
    for (int i = 0; i < 4; i++) {
        rx[i] = x[i] - cx; ry[i] = y[i] - cy;
        cl[i] = ang_class(rx[i], ry[i]);
    }
#define CE(i, j) { \
    int cd = cl[i] - cl[j]; \
    double cr = (double)rx[i] * (double)ry[j] - (double)ry[i] * (double)rx[j]; \
    bool gt = (cd > 0) || (cd == 0 && cr < 0.0);  /* ang_i > ang_j -> swap */ \
    float t; int ti; \
    t = x[i];  x[i]  = gt ? x[j]  : x[i];  x[j]  = gt ? t  : x[j]; \
    t = y[i];  y[i]  = gt ? y[j]  : y[i];  y[j]  = gt ? t  : y[j]; \
    t = rx[i]; rx[i] = gt ? rx[j] : rx[i]; rx[j] = gt ? t  : rx[j]; \
    t = ry[i]; ry[i] = gt ? ry[j] : ry[i]; ry[j] = gt ? t  : ry[j]; \
    ti = cl[i]; cl[i] = gt ? cl[j] : cl[i]; cl[j] = gt ? ti : cl[j]; \
}
    CE(0, 1) CE(2, 3) CE(0, 2) CE(1, 3) CE(1, 2)
#undef CE
#pragma unroll
    for (int k = 0; k < 4; k++) { out[k].x = x[k]; out[k].y = y[k]; }
}

// One Sutherland-Hodgman round, IN-PLACE in LDS. All emissions are
// unconditional ds_writes; invalid ones land in trash row 8 (branch-free).
__device__ __forceinline__ int clip_mid(float2 (*buf)[NT], V2 A, V2 B,
                                        int nv, int tid)
{
    float ex = B.x - A.x, ey = B.y - A.y;
    float qx[8], qy[8], d[8];
#pragma unroll
    for (int s = 0; s < 8; s++) {
        float2 v = buf[s][tid];
        qx[s] = v.x; qy[s] = v.y;
        d[s] = ex * (v.y - A.y) - ey * (v.x - A.x);
    }
    int cnt = 0;
#pragma unroll
    for (int idx = 0; idx < 8; idx++) {
        // next vertex: replicates poly[(idx+1) % max(nv,1)] with JAX index-clamp
        float nxx, nxy, dn;
        if (idx == 7) {
            bool w = (nv == 8);          // nv>8 -> index 8 clamps to slot 7 (self)
            nxx = w ? qx[0] : qx[7];
            nxy = w ? qy[0] : qy[7];
            dn  = w ? d[0]  : d[7];
        } else {
            bool w = ((idx + 1) == nv);
            nxx = w ? qx[0] : qx[idx + 1];
            nxy = w ? qy[0] : qy[idx + 1];
            dn  = w ? d[0]  : d[idx + 1];
        }
        bool active = idx < nv;
        bool in_cur = d[idx] >= 0.f;
        bool in_nxt = dn >= 0.f;
        float den = d[idx] - dn;
        den = (fabsf(den) < 1e-12f) ? 1e-12f : den;
        float t = __fdividef(d[idx], den);
        float ix = qx[idx] + t * (nxx - qx[idx]);
        float iy = qy[idx] + t * (nxy - qy[idx]);
        bool v0 = active && in_cur;
        bool v1 = active && (in_cur != in_nxt);
        int s0 = (v0 && cnt < 8) ? cnt : 8;
        buf[s0][tid] = make_float2(qx[idx], qy[idx]);
        cnt += v0 ? 1 : 0;
        int s1 = (v1 && cnt < 8) ? cnt : 8;
        buf[s1][tid] = make_float2(ix, iy);
        cnt += v1 ? 1 : 0;
    }
    return cnt;   // unclamped count, like the reference
}

// Final round: clip fused with shoelace over emitted points (no LDS writes).
// Emission order == slot order; wrap term added last == reference FP sum order.
__device__ __forceinline__ float clip_final(const float2 (*buf)[NT], V2 A, V2 B,
                                            int nv, int tid)
{
    float ex = B.x - A.x, ey = B.y - A.y;
    float qx[8], qy[8], d[8];
#pragma unroll
    for (int s = 0; s < 8; s++) {
        float2 v = buf[s][tid];
        qx[s] = v.x; qy[s] = v.y;
        d[s] = ex * (v.y - A.y) - ey * (v.x - A.x);
    }
    int cnt = 0;
    float sx = 0.f;
    float fx = 0.f, fy = 0.f;   // first kept point
    float px = 0.f, py = 0.f;   // prev kept point (slot <= 7)
#pragma unroll
    for (int idx = 0; idx < 8; idx++) {
        float nxx, nxy, dn;
        if (idx == 7) {
            bool w = (nv == 8);
            nxx = w ? qx[0] : qx[7];
            nxy = w ? qy[0] : qy[7];
            dn  = w ? d[0]  : d[7];
        } else {
            bool w = ((idx + 1) == nv);
            nxx = w ? qx[0] : qx[idx + 1];
            nxy = w ? qy[0] : qy[idx + 1];
            dn  = w ? d[0]  : d[idx + 1];
        }
        bool active = idx < nv;
        bool in_cur = d[idx] >= 0.f;
        bool in_nxt = dn >= 0.f;
        float den = d[idx] - dn;
        den = (fabsf(den) < 1e-12f) ? 1e-12f : den;
        float t = __fdividef(d[idx], den);
        float ix = qx[idx] + t * (nxx - qx[idx]);
        float iy = qy[idx] + t * (nxy - qy[idx]);
        bool v0 = active && in_cur;
        bool v1 = active && (in_cur != in_nxt);
        {
            bool w0 = (cnt == 0), wl = (cnt <= 7);
            if (v0) {
                fx = w0 ? qx[idx] : fx; fy = w0 ? qy[idx] : fy;
                sx += (!w0 && wl) ? (px * qy[idx] - qx[idx] * py) : 0.f;
                px = wl ? qx[idx] : px; py = wl ? qy[idx] : py;
            }
            cnt += v0 ? 1 : 0;
        }
        {
            bool w0 = (cnt == 0), wl = (cnt <= 7);
            if (v1) {
                fx = w0 ? ix : fx; fy = w0 ? iy : fy;
                sx += (!w0 && wl) ? (px * iy - ix * py) : 0.f;
                px = wl ? ix : px; py = wl ? iy : py;
            }
            cnt += v1 ? 1 : 0;
        }
    }
    // wrap term (ref: idx nv-1 pairs poly[0]); nv>8 -> slot7 pairs itself (0)
    if (cnt > 0 && cnt <= 8) sx += px * fy - fx * py;
    return 0.5f * fabsf(sx);
}

__global__ __launch_bounds__(256, 8) void poly_iou_kernel(
    const float* __restrict__ preds, const float* __restrict__ targets,
    float* __restrict__ out, int n)
{
    __shared__ float2 buf[9][NT];   // 18 KB: 8 slots + 1 trash row per thread
    int tid = threadIdx.x;
    int gid = blockIdx.x * NT + tid;
    if (gid >= n) return;

    const float4* p4 = reinterpret_cast<const float4*>(preds);
    const float4* t4 = reinterpret_cast<const float4*>(targets);
    float4 a0 = p4[2 * gid], a1 = p4[2 * gid + 1];
    float4 b0 = t4[2 * gid], b1 = t4[2 * gid + 1];

    V2 P[4], T[4];
    angle_sort4(a0, a1, P);
    angle_sort4(b0, b1, T);

    // ---- edge 0 (nv=4 compile-time): registers -> buf, branch-free emits ----
    int nv;
    {
        float ex = T[1].x - T[0].x, ey = T[1].y - T[0].y;
        float dd[4];
#pragma unroll
        for (int k = 0; k < 4; k++)
            dd[k] = ex * (P[k].y - T[0].y) - ey * (P[k].x - T[0].x);
        int cnt = 0;
#pragma unroll
        for (int idx = 0; idx < 4; idx++) {
            int j = (idx + 1) & 3;
            bool in_cur = dd[idx] >= 0.f;
            bool in_nxt = dd[j] >= 0.f;
            float den = dd[idx] - dd[j];
            den = (fabsf(den) < 1e-12f) ? 1e-12f : den;
            float t = __fdividef(dd[idx], den);
            float ix = P[idx].x + t * (P[j].x - P[idx].x);
            float iy = P[idx].y + t * (P[j].y - P[idx].y);
            bool v1 = (in_cur != in_nxt);
            int s0 = in_cur ? cnt : 8;              // cnt <= 7 here always
            buf[s0][tid] = make_float2(P[idx].x, P[idx].y);
            cnt += in_cur ? 1 : 0;
            int s1 = v1 ? cnt : 8;
            buf[s1][tid] = make_float2(ix, iy);
            cnt += v1 ? 1 : 0;
        }
        nv = cnt;
    }

    // ---- edges 1..2 in place; edge 3 fused with shoelace ----
    nv = clip_mid(buf, T[1], T[2], nv, tid);
    nv = clip_mid(buf, T[2], T[3], nv, tid);
    float inter = clip_final(buf, T[3], T[0], nv, tid);

    // ---- convex hull (gift wrap, serial scan — low VGPR pressure) ----
    V2 h[8];
#pragma unroll
    for (int k = 0; k < 4; k++) { h[k] = P[k]; h[4 + k] = T[k]; }

    int start = 0; V2 vs = h[0];
#pragma unroll
    for (int k = 1; k < 8; k++) {           // first-index argmin of y
        bool b = h[k].y < vs.y;
        start = b ? k : start;
        vs.x  = b ? h[k].x : vs.x;
        vs.y  = b ? h[k].y : vs.y;
    }

    V2 pc = vs; int cur = start; bool done = false; float harea = 0.f;
#pragma unroll 1
    for (int s = 0; s < 8; s++) {
        // most-clockwise ray from pc; farthest on collinear; first index on tie.
        // bx=by=0 start: first valid k takes via (c==0 && d2>bd), bd=0.
        int best = cur;
        float bx = 0.f, by = 0.f, bd = 0.f, px = pc.x, py = pc.y;
#pragma unroll
        for (int k = 0; k < 8; k++) {
            float rx = h[k].x - pc.x, ry = h[k].y - pc.y;
            float d2 = rx * rx + ry * ry;
            bool ok = d2 > 1e-12f;
            float c = bx * ry - by * rx;    // cross(best, k)
            bool take = ok && ((c < 0.f) || ((c == 0.f) && (d2 > bd)));
            best = take ? k : best;
            bx = take ? rx : bx; by = take ? ry : by; bd = take ? d2 : bd;
            px = take ? h[k].x : px; py = take ? h[k].y : py;
        }
        int nxt = done ? cur : best;
        V2 pv;
        pv.x = done ? pc.x : px;
        pv.y = done ? pc.y : py;
        harea += pc.x * pv.y - pv.x * pc.y;  // stay-steps add exact 0
        done = done || (nxt == start);
        pc = pv; cur = nxt;
        if (__all(done)) break;              // skipped steps contribute exact 0
    }
    harea += pc.x * vs.y - vs.x * pc.y;     // closure
    harea = 0.5f * fabsf(harea);

    float iou = (harea > 1e-12f) ? (inter / fmaxf(harea, 1e-12f)) : 0.f;
    out[gid] = 1.f - iou;
}

extern "C" void kernel_launch(void* const* d_in, const int* in_sizes, int n_in,
                              void* d_out, int out_size, void* d_ws, size_t ws_size,
                              hipStream_t stream) {
    const float* preds = (const float*)d_in[0];
    const float* targets = (const float*)d_in[1];
    float* out = (float*)d_out;
    int n = in_sizes[0] / 8;
    int block = NT;
    int grid = (n + block - 1) / block;
    hipLaunchKernelGGL(poly_iou_kernel, dim3(grid), dim3(block), 0, stream,
                       preds, targets, out, n);
}

// Round 9
// 33.588 us; speedup vs baseline: 1.2340x; 1.0045x over previous
//
#include <hip/hip_runtime.h>
#include <math.h>

struct V2 { float x, y; };

#define NT 128

// angle class matching atan2 range ordering: 0: y<0 (-pi,0); 1: y==0,x>=0 {0};
// 2: y>0 (0,pi); 3: y==0,x<0 {pi}
__device__ __forceinline__ int ang_class(float x, float y) {
    return (y < 0.f) ? 0 : ((y > 0.f) ? 2 : ((x >= 0.f) ? 1 : 3));
}

// Ascending sort of 4 points by exact atan2 ordering around the centroid,
// as a 5-comparator network. Comparator is exact (f64 cross), deviating from
// jnp.argsort only on exact angle ties (measure zero).
__device__ __forceinline__ void angle_sort4(float4 lo, float4 hi, V2 out[4]) {
    float x[4] = {lo.x, lo.z, hi.x, hi.z};
    float y[4] = {lo.y, lo.w, hi.y, hi.w};
    float cx = (((x[0] + x[1]) + x[2]) + x[3]) * 0.25f;
    float cy = (((y[0] + y[1]) + y[2]) + y[3]) * 0.25f;
    float rx[4], ry[4]; int cl[4];
#pragma unroll
    for (int i = 0; i < 4; i++) {
        rx[i] = x[i] - cx; ry[i] = y[i] - cy;
        cl[i] = ang_class(rx[i], ry[i]);
    }
#define CE(i, j) { \
    int cd = cl[i] - cl[j]; \
    double cr = (double)rx[i] * (double)ry[j] - (double)ry[i] * (double)rx[j]; \
    bool gt = (cd > 0) || (cd == 0 && cr < 0.0);  /* ang_i > ang_j -> swap */ \
    float t; int ti; \
    t = x[i];  x[i]  = gt ? x[j]  : x[i];  x[j]  = gt ? t  : x[j]; \
    t = y[i];  y[i]  = gt ? y[j]  : y[i];  y[j]  = gt ? t  : y[j]; \
    t = rx[i]; rx[i] = gt ? rx[j] : rx[i]; rx[j] = gt ? t  : rx[j]; \
    t = ry[i]; ry[i] = gt ? ry[j] : ry[i]; ry[j] = gt ? t  : ry[j]; \
    ti = cl[i]; cl[i] = gt ? cl[j] : cl[i]; cl[j] = gt ? ti : cl[j]; \
}
    CE(0, 1) CE(2, 3) CE(0, 2) CE(1, 3) CE(1, 2)
#undef CE
#pragma unroll
    for (int k = 0; k < 4; k++) { out[k].x = x[k]; out[k].y = y[k]; }
}

// One Sutherland-Hodgman round, IN-PLACE in LDS. All emissions are
// unconditional ds_writes; invalid ones land in trash row 8 (branch-free).
__device__ __forceinline__ int clip_mid(float2 (*buf)[NT], V2 A, V2 B,
                                        int nv, int tid)
{
    float ex = B.x - A.x, ey = B.y - A.y;
    float qx[8], qy[8], d[8];
#pragma unroll
    for (int s = 0; s < 8; s++) {
        float2 v = buf[s][tid];
        qx[s] = v.x; qy[s] = v.y;
        d[s] = ex * (v.y - A.y) - ey * (v.x - A.x);
    }
    int cnt = 0;
#pragma unroll
    for (int idx = 0; idx < 8; idx++) {
        // next vertex: replicates poly[(idx+1) % max(nv,1)] with JAX index-clamp
        float nxx, nxy, dn;
        if (idx == 7) {
            bool w = (nv == 8);          // nv>8 -> index 8 clamps to slot 7 (self)
            nxx = w ? qx[0] : qx[7];
            nxy = w ? qy[0] : qy[7];
            dn  = w ? d[0]  : d[7];
        } else {
            bool w = ((idx + 1) == nv);
            nxx = w ? qx[0] : qx[idx + 1];
            nxy = w ? qy[0] : qy[idx + 1];
            dn  = w ? d[0]  : d[idx + 1];
        }
        bool active = idx < nv;
        bool in_cur = d[idx] >= 0.f;
        bool in_nxt = dn >= 0.f;
        float den = d[idx] - dn;
        den = (fabsf(den) < 1e-12f) ? 1e-12f : den;
        float t = __fdividef(d[idx], den);
        float ix = qx[idx] + t * (nxx - qx[idx]);
        float iy = qy[idx] + t * (nxy - qy[idx]);
        bool v0 = active && in_cur;
        bool v1 = active && (in_cur != in_nxt);
        int s0 = (v0 && cnt < 8) ? cnt : 8;
        buf[s0][tid] = make_float2(qx[idx], qy[idx]);
        cnt += v0 ? 1 : 0;
        int s1 = (v1 && cnt < 8) ? cnt : 8;
        buf[s1][tid] = make_float2(ix, iy);
        cnt += v1 ? 1 : 0;
    }
    return cnt;   // unclamped count, like the reference
}

// Final round: clip fused with shoelace over emitted points (no LDS writes).
// Emission order == slot order; wrap term added last == reference FP sum order.
__device__ __forceinline__ float clip_final(const float2 (*buf)[NT], V2 A, V2 B,
                                            int nv, int tid)
{
    float ex = B.x - A.x, ey = B.y - A.y;
    float qx[8], qy[8], d[8];
#pragma unroll
    for (int s = 0; s < 8; s++) {
        float2 v = buf[s][tid];
        qx[s] = v.x; qy[s] = v.y;
        d[s] = ex * (v.y - A.y) - ey * (v.x - A.x);
    }
    int cnt = 0;
    float sx = 0.f;
    float fx = 0.f, fy = 0.f;   // first kept point
    float px = 0.f, py = 0.f;   // prev kept point (slot <= 7)
#pragma unroll
    for (int idx = 0; idx < 8; idx++) {
        float nxx, nxy, dn;
        if (idx == 7) {
            bool w = (nv == 8);
            nxx = w ? qx[0] : qx[7];
            nxy = w ? qy[0] : qy[7];
            dn  = w ? d[0]  : d[7];
        } else {
            bool w = ((idx + 1) == nv);
            nxx = w ? qx[0] : qx[idx + 1];
            nxy = w ? qy[0] : qy[idx + 1];
            dn  = w ? d[0]  : d[idx + 1];
        }
        bool active = idx < nv;
        bool in_cur = d[idx] >= 0.f;
        bool in_nxt = dn >= 0.f;
        float den = d[idx] - dn;
        den = (fabsf(den) < 1e-12f) ? 1e-12f : den;
        float t = __fdividef(d[idx], den);
        float ix = qx[idx] + t * (nxx - qx[idx]);
        float iy = qy[idx] + t * (nxy - qy[idx]);
        bool v0 = active && in_cur;
        bool v1 = active && (in_cur != in_nxt);
        {
            bool w0 = (cnt == 0), wl = (cnt <= 7);
            if (v0) {
                fx = w0 ? qx[idx] : fx; fy = w0 ? qy[idx] : fy;
                sx += (!w0 && wl) ? (px * qy[idx] - qx[idx] * py) : 0.f;
                px = wl ? qx[idx] : px; py = wl ? qy[idx] : py;
            }
            cnt += v0 ? 1 : 0;
        }
        {
            bool w0 = (cnt == 0), wl = (cnt <= 7);
            if (v1) {
                fx = w0 ? ix : fx; fy = w0 ? iy : fy;
                sx += (!w0 && wl) ? (px * iy - ix * py) : 0.f;
                px = wl ? ix : px; py = wl ? iy : py;
            }
            cnt += v1 ? 1 : 0;
        }
    }
    // wrap term (ref: idx nv-1 pairs poly[0]); nv>8 -> slot7 pairs itself (0)
    if (cnt > 0 && cnt <= 8) sx += px * fy - fx * py;
    return 0.5f * fabsf(sx);
}

__global__ __launch_bounds__(NT, 8) void poly_iou_kernel(
    const float* __restrict__ preds, const float* __restrict__ targets,
    float* __restrict__ out, int n)
{
    __shared__ float2 buf[9][NT];   // 9 KB: 8 slots + 1 trash row per thread
    int tid = threadIdx.x;
    int gid = blockIdx.x * NT + tid;
    if (gid >= n) return;

    const float4* p4 = reinterpret_cast<const float4*>(preds);
    const float4* t4 = reinterpret_cast<const float4*>(targets);
    float4 a0 = p4[2 * gid], a1 = p4[2 * gid + 1];
    float4 b0 = t4[2 * gid], b1 = t4[2 * gid + 1];

    V2 P[4], T[4];
    angle_sort4(a0, a1, P);
    angle_sort4(b0, b1, T);

    // ---- edge 0 (nv=4 compile-time): registers -> buf, branch-free emits ----
    int nv;
    {
        float ex = T[1].x - T[0].x, ey = T[1].y - T[0].y;
        float dd[4];
#pragma unroll
        for (int k = 0; k < 4; k++)
            dd[k] = ex * (P[k].y - T[0].y) - ey * (P[k].x - T[0].x);
        int cnt = 0;
#pragma unroll
        for (int idx = 0; idx < 4; idx++) {
            int j = (idx + 1) & 3;
            bool in_cur = dd[idx] >= 0.f;
            bool in_nxt = dd[j] >= 0.f;
            float den = dd[idx] - dd[j];
            den = (fabsf(den) < 1e-12f) ? 1e-12f : den;
            float t = __fdividef(dd[idx], den);
            float ix = P[idx].x + t * (P[j].x - P[idx].x);
            float iy = P[idx].y + t * (P[j].y - P[idx].y);
            bool v1 = (in_cur != in_nxt);
            int s0 = in_cur ? cnt : 8;              // cnt <= 7 here always
            buf[s0][tid] = make_float2(P[idx].x, P[idx].y);
            cnt += in_cur ? 1 : 0;
            int s1 = v1 ? cnt : 8;
            buf[s1][tid] = make_float2(ix, iy);
            cnt += v1 ? 1 : 0;
        }
        nv = cnt;
    }

    // ---- edges 1..2 in place; edge 3 fused with shoelace ----
    nv = clip_mid(buf, T[1], T[2], nv, tid);
    nv = clip_mid(buf, T[2], T[3], nv, tid);
    float inter = clip_final(buf, T[3], T[0], nv, tid);

    // ---- convex hull (gift wrap, serial scan — low VGPR pressure) ----
    V2 h[8];
#pragma unroll
    for (int k = 0; k < 4; k++) { h[k] = P[k]; h[4 + k] = T[k]; }

    int start = 0; V2 vs = h[0];
#pragma unroll
    for (int k = 1; k < 8; k++) {           // first-index argmin of y
        bool b = h[k].y < vs.y;
        start = b ? k : start;
        vs.x  = b ? h[k].x : vs.x;
        vs.y  = b ? h[k].y : vs.y;
    }

    V2 pc = vs; int cur = start; bool done = false; float harea = 0.f;
#pragma unroll 1
    for (int s = 0; s < 8; s++) {
        // most-clockwise ray from pc; farthest on collinear; first index on tie.
        // bx=by=0 start: first valid k takes via (c==0 && d2>bd), bd=0.
        int best = cur;
        float bx = 0.f, by = 0.f, bd = 0.f, px = pc.x, py = pc.y;
#pragma unroll
        for (int k = 0; k < 8; k++) {
            float rx = h[k].x - pc.x, ry = h[k].y - pc.y;
            float d2 = rx * rx + ry * ry;
            bool ok = d2 > 1e-12f;
            float c = bx * ry - by * rx;    // cross(best, k)
            bool take = ok && ((c < 0.f) || ((c == 0.f) && (d2 > bd)));
            best = take ? k : best;
            bx = take ? rx : bx; by = take ? ry : by; bd = take ? d2 : bd;
            px = take ? h[k].x : px; py = take ? h[k].y : py;
        }
        int nxt = done ? cur : best;
        V2 pv;
        pv.x = done ? pc.x : px;
        pv.y = done ? pc.y : py;
        harea += pc.x * pv.y - pv.x * pc.y;  // stay-steps add exact 0
        done = done || (nxt == start);
        pc = pv; cur = nxt;
        if (__all(done)) break;              // skipped steps contribute exact 0
    }
    harea += pc.x * vs.y - vs.x * pc.y;     // closure
    harea = 0.5f * fabsf(harea);

    float iou = (harea > 1e-12f) ? (inter / fmaxf(harea, 1e-12f)) : 0.f;
    out[gid] = 1.f - iou;
}

extern "C" void kernel_launch(void* const* d_in, const int* in_sizes, int n_in,
                              void* d_out, int out_size, void* d_ws, size_t ws_size,
                              hipStream_t stream) {
    const float* preds = (const float*)d_in[0];
    const float* targets = (const float*)d_in[1];
    float* out = (float*)d_out;
    int n = in_sizes[0] / 8;
    int block = NT;
    int grid = (n + block - 1) / block;
    hipLaunchKernelGGL(poly_iou_kernel, dim3(grid), dim3(block), 0, stream,
                       preds, targets, out, n);
}